// Round 4
// baseline (216.051 us; speedup 1.0000x reference)
//
#include <hip/hip_runtime.h>
#include <math.h>

#define NB 256
#define NF 8
#define NS 200
#define ND 64
#define NH 36
#define EPSV 1e-3f

// ws float-offset layout:
#define WS_SUM 0                      // [0,288)    per-(f,h) sum
#define WS_SQ  288                    // [288,576)  per-(f,h) sumsq
#define WS_QT  1152                   // 2048*48 floats: qt[b,f,h] (h padded to 48)
#define WS_WK  (1152 + 2048 * 48)     // bf16 WkT[f][h(48)][d(64)] = (W1-W3)^T

typedef __attribute__((ext_vector_type(8))) short short8;
typedef __attribute__((ext_vector_type(4))) float f32x4;
typedef __attribute__((ext_vector_type(4))) int int4v;

__device__ __forceinline__ unsigned short f32_to_bf16_rne(float x) {
    unsigned u = __float_as_uint(x);
    unsigned r = u + 0x7FFFu + ((u >> 16) & 1u);
    return (unsigned short)(r >> 16);
}
__device__ __forceinline__ float bf16_to_f32(unsigned short h) {
    return __uint_as_float(((unsigned)h) << 16);
}
// Pack 8 floats -> 8 bf16 (truncation) in 4 v_perm_b32.
__device__ __forceinline__ short8 pack8(float4 a, float4 b) {
    int4v t;
    t[0] = (int)__builtin_amdgcn_perm(__float_as_uint(a.y), __float_as_uint(a.x), 0x07060302u);
    t[1] = (int)__builtin_amdgcn_perm(__float_as_uint(a.w), __float_as_uint(a.z), 0x07060302u);
    t[2] = (int)__builtin_amdgcn_perm(__float_as_uint(b.y), __float_as_uint(b.x), 0x07060302u);
    t[3] = (int)__builtin_amdgcn_perm(__float_as_uint(b.w), __float_as_uint(b.z), 0x07060302u);
    return __builtin_bit_cast(short8, t);
}

// blocks 0..255: qt[b,*,*]. blocks 256..263: WkT bf16 (RNE) for f=blk-256.
__global__ __launch_bounds__(256) void k_prep(
    const float* __restrict__ query, const float* __restrict__ W_h,
    const float* __restrict__ b_h, float* __restrict__ ws)
{
    const int blk = blockIdx.x, tid = threadIdx.x;
    if (blk < NB) {
        __shared__ float qs[NF * ND];
        for (int i = tid; i < NF * ND; i += 256)
            qs[i] = query[(size_t)blk * NF * ND + i];
        __syncthreads();
        for (int i = tid; i < NF * 48; i += 256) {
            int f = i / 48, h = i - f * 48;
            float acc = 0.f;
            if (h < NH) {
                const float* Wf = W_h + (size_t)f * (3 * ND * NH);
                acc = b_h[f * NH + h];
                for (int d = 0; d < ND; ++d)
                    acc += qs[f * ND + d] * (Wf[(ND + d) * NH + h] + Wf[(2 * ND + d) * NH + h]);
            }
            ws[WS_QT + (size_t)(blk * NF + f) * 48 + h] = acc;
        }
    } else {
        const int f = blk - NB;
        const float* Wf = W_h + (size_t)f * (3 * ND * NH);
        unsigned short* wk = (unsigned short*)(ws + WS_WK) + f * (48 * ND);
        for (int i = tid; i < 48 * ND; i += 256) {
            int h = i >> 6, d = i & 63;
            float v = (h < NH) ? (Wf[d * NH + h] - Wf[(2 * ND + d) * NH + h]) : 0.f;
            wk[h * ND + d] = f32_to_bf16_rne(v);
        }
    }
}

// grid = 1024, each block: 2 batches (b0, b0+1) for one f. One clean round at 4 blk/CU.
__global__ __launch_bounds__(256, 4) void k_stats(
    const float* __restrict__ key, float* __restrict__ ws)
{
    const int blk = blockIdx.x;
    const int f = blk & (NF - 1);
    const int b0 = (blk >> 3) * 2;
    const int tid = threadIdx.x;
    const int lane = tid & 63;
    const int wv = tid >> 6;
    const int col = lane & 15;
    const int quad = lane >> 4;

    __shared__ float sumP[2][48], sqP[2][48];
    if (tid < 96) { int p = tid / 48, h = tid - 48 * p; sumP[p][h] = 0.f; sqP[p][h] = 0.f; }
    __syncthreads();

    const unsigned short* wk = (const unsigned short*)(ws + WS_WK) + f * (48 * ND);
    const float* kb0 = key + (size_t)(b0 * NF + f) * (NS * ND);
    const float* kb1 = kb0 + (size_t)NF * NS * ND;

    short8 bfr[3][2];
    #pragma unroll
    for (int nt = 0; nt < 3; ++nt)
        #pragma unroll
        for (int ks = 0; ks < 2; ++ks)
            bfr[nt][ks] = *(const short8*)&wk[(nt * 16 + col) * ND + ks * 32 + quad * 8];

    float s1[2][3] = {{0.f,0.f,0.f},{0.f,0.f,0.f}};
    float s2[2][3] = {{0.f,0.f,0.f},{0.f,0.f,0.f}};

    // mt = wv + 4*i, i=0..2 -> rows 0..191 (all valid)
    #pragma unroll
    for (int i = 0; i < 3; ++i) {
        const int s = 16 * (wv + 4 * i) + col;
        const size_t off = (size_t)s * ND + quad * 8;
        #pragma unroll
        for (int p = 0; p < 2; ++p) {
            const float4* ptr = (const float4*)((p ? kb1 : kb0) + off);
            float4 a0 = ptr[0], a1 = ptr[1], c0 = ptr[8], c1 = ptr[9];
            short8 fa = pack8(a0, a1);
            short8 fb = pack8(c0, c1);
            #pragma unroll
            for (int nt = 0; nt < 3; ++nt) {
                f32x4 acc = {0.f, 0.f, 0.f, 0.f};
                acc = __builtin_amdgcn_mfma_f32_16x16x32_bf16(fa, bfr[nt][0], acc, 0, 0, 0);
                acc = __builtin_amdgcn_mfma_f32_16x16x32_bf16(fb, bfr[nt][1], acc, 0, 0, 0);
                #pragma unroll
                for (int r = 0; r < 4; ++r) { float v = acc[r]; s1[p][nt] += v; s2[p][nt] += v * v; }
            }
        }
    }
    // tail tile mt=12 (rows 192..207; rows>=200 zeroed): wave 0 only
    if (wv == 0) {
        const int s = 192 + col;
        #pragma unroll
        for (int p = 0; p < 2; ++p) {
            short8 fa = {0,0,0,0,0,0,0,0}, fb = {0,0,0,0,0,0,0,0};
            if (col < 8) {
                const float4* ptr = (const float4*)((p ? kb1 : kb0) + (size_t)s * ND + quad * 8);
                float4 a0 = ptr[0], a1 = ptr[1], c0 = ptr[8], c1 = ptr[9];
                fa = pack8(a0, a1); fb = pack8(c0, c1);
            }
            #pragma unroll
            for (int nt = 0; nt < 3; ++nt) {
                f32x4 acc = {0.f, 0.f, 0.f, 0.f};
                acc = __builtin_amdgcn_mfma_f32_16x16x32_bf16(fa, bfr[nt][0], acc, 0, 0, 0);
                acc = __builtin_amdgcn_mfma_f32_16x16x32_bf16(fb, bfr[nt][1], acc, 0, 0, 0);
                #pragma unroll
                for (int r = 0; r < 4; ++r) { float v = acc[r]; s1[p][nt] += v; s2[p][nt] += v * v; }
            }
        }
    }
    #pragma unroll
    for (int p = 0; p < 2; ++p)
        #pragma unroll
        for (int nt = 0; nt < 3; ++nt) {
            float a = s1[p][nt], c = s2[p][nt];
            a += __shfl_xor(a, 16, 64); a += __shfl_xor(a, 32, 64);
            c += __shfl_xor(c, 16, 64); c += __shfl_xor(c, 32, 64);
            if (quad == 0) {
                atomicAdd(&sumP[p][nt * 16 + col], a);
                atomicAdd(&sqP[p][nt * 16 + col], c);
            }
        }
    __syncthreads();
    if (tid < 72) {
        const int p = (tid >= NH) ? 1 : 0;
        const int h = tid - NH * p;
        const float S1 = sumP[p][h], S2 = sqP[p][h];
        const float qt = ws[WS_QT + (size_t)((b0 + p) * NF + f) * 48 + h];
        atomicAdd(&ws[WS_SUM + f * NH + h], S1 + 200.f * qt);
        atomicAdd(&ws[WS_SQ  + f * NH + h], S2 + 2.f * qt * S1 + 200.f * qt * qt);
    }
}

// grid = 1024, 2 batches per block processed sequentially (shared f-state hoisted).
__global__ __launch_bounds__(256, 4) void k_attn(
    const float* __restrict__ key, const float* __restrict__ alpha,
    const float* __restrict__ W_o, const float* __restrict__ b_o,
    const int* __restrict__ seqn, const float* __restrict__ ws,
    float* __restrict__ out)
{
    const int blk = blockIdx.x;
    const int f = blk & (NF - 1);
    const int b0 = (blk >> 3) * 2;
    const int tid = threadIdx.x;
    const int lane = tid & 63;
    const int wv = tid >> 6;
    const int col = lane & 15;
    const int quad = lane >> 4;

    __shared__ float sw[208];
    __shared__ float redM[4], redS[4];
    __shared__ float pout[4][64];

    const unsigned short* wk = (const unsigned short*)(ws + WS_WK) + f * (48 * ND);
    const float inv_n = 1.f / (float)(NB * NS);

    short8 bfr[3][2];
    float mn[3], iv[3], wo[3];
    #pragma unroll
    for (int nt = 0; nt < 3; ++nt) {
        #pragma unroll
        for (int ks = 0; ks < 2; ++ks)
            bfr[nt][ks] = *(const short8*)&wk[(nt * 16 + col) * ND + ks * 32 + quad * 8];
        const int hh = nt * 16 + col;
        const bool hv = hh < NH;
        const int hc = hv ? hh : 0;
        const float sm = ws[WS_SUM + f * NH + hc];
        const float sq = ws[WS_SQ + f * NH + hc];
        const float m = sm * inv_n;
        mn[nt] = m;
        iv[nt] = rsqrtf(fmaxf(sq * inv_n - m * m, 0.f) + EPSV);
        wo[nt] = hv ? W_o[f * NH + hh] : 0.f;
    }
    const float alf = alpha[f];
    const float bo = b_o[f];

    for (int p = 0; p < 2; ++p) {
        const int bf = (b0 + p) * NF + f;
        const float* kbase = key + (size_t)bf * (NS * ND);
        float qv[3];
        #pragma unroll
        for (int nt = 0; nt < 3; ++nt)
            qv[nt] = ws[WS_QT + (size_t)bf * 48 + nt * 16 + col];
        const int sq_n = seqn[bf];

        short8 kah[4][2];
        // main tiles i=0..2 (rows 0..191)
        #pragma unroll
        for (int i = 0; i < 3; ++i) {
            const int mt = wv + 4 * i;
            const int s = 16 * mt + col;
            const float4* ptr = (const float4*)(kbase + (size_t)s * ND + quad * 8);
            float4 a0 = ptr[0], a1 = ptr[1], c0 = ptr[8], c1 = ptr[9];
            kah[i][0] = pack8(a0, a1);
            kah[i][1] = pack8(c0, c1);
            float part[4] = {0.f, 0.f, 0.f, 0.f};
            #pragma unroll
            for (int nt = 0; nt < 3; ++nt) {
                f32x4 acc = {qv[nt], qv[nt], qv[nt], qv[nt]};
                acc = __builtin_amdgcn_mfma_f32_16x16x32_bf16(kah[i][0], bfr[nt][0], acc, 0, 0, 0);
                acc = __builtin_amdgcn_mfma_f32_16x16x32_bf16(kah[i][1], bfr[nt][1], acc, 0, 0, 0);
                #pragma unroll
                for (int r = 0; r < 4; ++r) {
                    const float h = acc[r];
                    const float pg = 1.f / (1.f + __expf(-(h - mn[nt]) * iv[nt]));
                    part[r] += (alf + (1.f - alf) * pg) * h * wo[nt];
                }
            }
            #pragma unroll
            for (int r = 0; r < 4; ++r) {
                float v = part[r];
                v += __shfl_xor(v, 1, 64); v += __shfl_xor(v, 2, 64);
                v += __shfl_xor(v, 4, 64); v += __shfl_xor(v, 8, 64);
                if (col == 0) sw[16 * mt + quad * 4 + r] = v + bo;
            }
        }
        // tail tile mt=12 (wave 0)
        if (wv == 0) {
            kah[3][0] = (short8){0,0,0,0,0,0,0,0};
            kah[3][1] = (short8){0,0,0,0,0,0,0,0};
            if (col < 8) {
                const float4* ptr = (const float4*)(kbase + (size_t)(192 + col) * ND + quad * 8);
                float4 a0 = ptr[0], a1 = ptr[1], c0 = ptr[8], c1 = ptr[9];
                kah[3][0] = pack8(a0, a1);
                kah[3][1] = pack8(c0, c1);
            }
            float part[4] = {0.f, 0.f, 0.f, 0.f};
            #pragma unroll
            for (int nt = 0; nt < 3; ++nt) {
                f32x4 acc = {qv[nt], qv[nt], qv[nt], qv[nt]};
                acc = __builtin_amdgcn_mfma_f32_16x16x32_bf16(kah[3][0], bfr[nt][0], acc, 0, 0, 0);
                acc = __builtin_amdgcn_mfma_f32_16x16x32_bf16(kah[3][1], bfr[nt][1], acc, 0, 0, 0);
                #pragma unroll
                for (int r = 0; r < 4; ++r) {
                    const float h = acc[r];
                    const float pg = 1.f / (1.f + __expf(-(h - mn[nt]) * iv[nt]));
                    part[r] += (alf + (1.f - alf) * pg) * h * wo[nt];
                }
            }
            #pragma unroll
            for (int r = 0; r < 4; ++r) {
                float v = part[r];
                v += __shfl_xor(v, 1, 64); v += __shfl_xor(v, 2, 64);
                v += __shfl_xor(v, 4, 64); v += __shfl_xor(v, 8, 64);
                const int srow = 192 + quad * 4 + r;
                if (col == 0 && srow < NS) sw[srow] = v + bo;
            }
        }
        __syncthreads();

        // softmax over s
        const bool valid = (tid < NS) && (tid < sq_n);
        const float sc = valid ? sw[tid] : -1e30f;
        float m = sc;
        m = fmaxf(m, __shfl_xor(m, 1, 64));  m = fmaxf(m, __shfl_xor(m, 2, 64));
        m = fmaxf(m, __shfl_xor(m, 4, 64));  m = fmaxf(m, __shfl_xor(m, 8, 64));
        m = fmaxf(m, __shfl_xor(m, 16, 64)); m = fmaxf(m, __shfl_xor(m, 32, 64));
        if (lane == 0) redM[wv] = m;
        __syncthreads();
        const float maxv = fmaxf(fmaxf(redM[0], redM[1]), fmaxf(redM[2], redM[3]));
        const float e = valid ? __expf(sc - maxv) : 0.f;
        float l = e;
        l += __shfl_xor(l, 1, 64);  l += __shfl_xor(l, 2, 64);
        l += __shfl_xor(l, 4, 64);  l += __shfl_xor(l, 8, 64);
        l += __shfl_xor(l, 16, 64); l += __shfl_xor(l, 32, 64);
        if (lane == 0) redS[wv] = l;
        __syncthreads();
        const float isum = 1.f / (redS[0] + redS[1] + redS[2] + redS[3]);
        if (tid < 208) sw[tid] = e * isum;   // rows 200..207 -> e==0
        __syncthreads();

        // out = attn @ key from retained bf16 fragments
        float po0[8] = {0,0,0,0,0,0,0,0}, po1[8] = {0,0,0,0,0,0,0,0};
        #pragma unroll
        for (int i = 0; i < 3; ++i) {
            const float w = sw[16 * (wv + 4 * i) + col];
            #pragma unroll
            for (int j = 0; j < 8; ++j) {
                po0[j] += w * bf16_to_f32((unsigned short)kah[i][0][j]);
                po1[j] += w * bf16_to_f32((unsigned short)kah[i][1][j]);
            }
        }
        if (wv == 0) {
            const float w = sw[192 + col];
            #pragma unroll
            for (int j = 0; j < 8; ++j) {
                po0[j] += w * bf16_to_f32((unsigned short)kah[3][0][j]);
                po1[j] += w * bf16_to_f32((unsigned short)kah[3][1][j]);
            }
        }
        #pragma unroll
        for (int off = 1; off <= 8; off <<= 1) {
            #pragma unroll
            for (int j = 0; j < 8; ++j) {
                po0[j] += __shfl_xor(po0[j], off, 64);
                po1[j] += __shfl_xor(po1[j], off, 64);
            }
        }
        if (col == 0) {
            #pragma unroll
            for (int j = 0; j < 8; ++j) {
                pout[wv][quad * 8 + j] = po0[j];
                pout[wv][32 + quad * 8 + j] = po1[j];
            }
        }
        __syncthreads();
        if (tid < 64)
            out[(size_t)bf * ND + tid] =
                pout[0][tid] + pout[1][tid] + pout[2][tid] + pout[3][tid];
    }
}

extern "C" void kernel_launch(void* const* d_in, const int* in_sizes, int n_in,
                              void* d_out, int out_size, void* d_ws, size_t ws_size,
                              hipStream_t stream) {
    const float* query = (const float*)d_in[0];
    const float* key   = (const float*)d_in[1];
    const float* W_h   = (const float*)d_in[2];
    const float* b_h   = (const float*)d_in[3];
    const float* alpha = (const float*)d_in[4];
    const float* W_o   = (const float*)d_in[5];
    const float* b_o   = (const float*)d_in[6];
    const int*   seqn  = (const int*)d_in[7];
    float* out = (float*)d_out;
    float* ws  = (float*)d_ws;

    hipMemsetAsync(ws, 0, 576 * sizeof(float), stream);
    k_prep<<<NB + NF, 256, 0, stream>>>(query, W_h, b_h, ws);
    k_stats<<<NB * NF / 2, 256, 0, stream>>>(key, ws);
    k_attn<<<NB * NF / 2, 256, 0, stream>>>(key, alpha, W_o, b_o, seqn, ws, out);
}